// Round 18
// baseline (811.866 us; speedup 1.0000x reference)
//
#include <hip/hip_runtime.h>
#include <cstddef>

#define BATCH 16
#define CH    128
#define NPTS  2048
#define KNN   9

typedef const __attribute__((address_space(1))) void* gptr_t;
typedef __attribute__((address_space(3))) void* lptr_t;

// ---------- K0: transpose x (B,C,N) -> xT (B,N,C) ----------
__global__ void k_transpose(const float* __restrict__ x, float* __restrict__ xT) {
  __shared__ float tile[32][33];
  int b = blockIdx.z;
  int n0 = blockIdx.x * 32, c0 = blockIdx.y * 32;
  int tx = threadIdx.x, ty = threadIdx.y;
#pragma unroll
  for (int i = 0; i < 4; ++i) {
    int cc = c0 + ty + i * 8;
    tile[ty + i * 8][tx] = x[((size_t)b * CH + cc) * NPTS + n0 + tx];
  }
  __syncthreads();
#pragma unroll
  for (int i = 0; i < 4; ++i) {
    int nn = n0 + ty + i * 8;
    xT[((size_t)b * NPTS + nn) * CH + c0 + tx] = tile[tx][ty + i * 8];
  }
}

// ---------- K0b: xx via numpy AVX512 pairwise-sum model (bit-exact, verified) ----------
__global__ void k_xx_pw(const float* __restrict__ x, float* __restrict__ xx) {
  int g = blockIdx.x * 256 + threadIdx.x;   // b*NPTS + n
  int b = g >> 11, n = g & (NPTS - 1);
  const float* p = x + (size_t)b * CH * NPTS + n;
  float s[128];
#pragma unroll
  for (int c = 0; c < 128; ++c) {
    float v = p[(size_t)c * NPTS];
    s[c] = __fmul_rn(v, v);
  }
  float lane[16];
#pragma unroll
  for (int l = 0; l < 16; ++l) {
    lane[l] = __fadd_rn(
        __fadd_rn(__fadd_rn(s[l], s[16 + l]), __fadd_rn(s[32 + l], s[48 + l])),
        __fadd_rn(__fadd_rn(s[64 + l], s[80 + l]), __fadd_rn(s[96 + l], s[112 + l])));
  }
  float m8[8];
#pragma unroll
  for (int i = 0; i < 8; ++i) m8[i] = __fadd_rn(lane[i], lane[i + 8]);
  float n4[4];
#pragma unroll
  for (int i = 0; i < 4; ++i) n4[i] = __fadd_rn(m8[i], m8[i + 4]);
  float p2[2];
#pragma unroll
  for (int i = 0; i < 2; ++i) p2[i] = __fadd_rn(n4[i], n4[i + 2]);
  xx[g] = __fadd_rn(p2[0], p2[1]);
}

// ---------- K1: 64x64 tile + K-split double-buffered colT (r15 structure, ~521us) ----------
__global__ __launch_bounds__(256) void k_knn_np(const float* __restrict__ x,
                                                const float* __restrict__ xx,
                                                int* __restrict__ idxout) {
  __shared__ __align__(16) char smraw[65536];
  float (*rowT)[64] = (float (*)[64])smraw;                       // [128][64] 32KB
  float* colA = (float*)(smraw + 32768);                          // [64][64] 16KB
  float* colB = (float*)(smraw + 49152);                          // [64][64] 16KB
  float (*mv)[145] = (float (*)[145])smraw;                       // merge overlay
  unsigned short (*mi)[145] = (unsigned short (*)[145])(smraw + 37120);

  int b = blockIdx.y;
  int n0 = blockIdx.x * 64;
  int tid = threadIdx.x;
  int tx = tid & 15, ty = tid >> 4;

  const float* gb = x + (size_t)b * CH * NPTS;

#pragma unroll
  for (int i = 0; i < 8; ++i) {
    int e = i * 1024 + tid * 4;
    const float* ga = gb + (size_t)(e >> 6) * NPTS + n0 + (e & 63);
    __builtin_amdgcn_global_load_lds((gptr_t)ga, (lptr_t)(&rowT[0][0] + e), 16, 0, 0);
  }

  float tv[4][9];
  int   ti[4][9];
#pragma unroll
  for (int m = 0; m < 4; ++m)
#pragma unroll
    for (int s = 0; s < 9; ++s) { tv[m][s] = -3.4e38f; ti[m][s] = 0x7fffffff; }

  float xr[4];
#pragma unroll
  for (int m = 0; m < 4; ++m) xr[m] = xx[(size_t)b * NPTS + n0 + ty * 4 + m];

#pragma unroll
  for (int i = 0; i < 4; ++i) {
    int e = i * 1024 + tid * 4;
    const float* ga = gb + (size_t)(e >> 6) * NPTS + 0 + (e & 63);
    __builtin_amdgcn_global_load_lds((gptr_t)ga, (lptr_t)(colA + e), 16, 0, 0);
  }

  for (int jt = 0; jt < NPTS; jt += 64) {
    int jnext = (jt + 64) & (NPTS - 1);

    __builtin_amdgcn_s_barrier();
#pragma unroll
    for (int i = 0; i < 4; ++i) {
      int e = i * 1024 + tid * 4;
      const float* ga = gb + (size_t)(64 + (e >> 6)) * NPTS + jt + (e & 63);
      __builtin_amdgcn_global_load_lds((gptr_t)ga, (lptr_t)(colB + e), 16, 0, 0);
    }
    asm volatile("s_waitcnt vmcnt(4)" ::: "memory");
    __builtin_amdgcn_s_barrier();

    float acc[4][4];
#pragma unroll
    for (int m = 0; m < 4; ++m)
#pragma unroll
      for (int nn = 0; nn < 4; ++nn) acc[m][nn] = 0.f;

#pragma unroll 8
    for (int k2 = 0; k2 < 64; ++k2) {
      float a[4], bv[4];
      *(float4*)a  = *(const float4*)&rowT[k2][ty * 4];
      *(float4*)bv = *(const float4*)(colA + k2 * 64 + tx * 4);
#pragma unroll
      for (int m = 0; m < 4; ++m)
#pragma unroll
        for (int nn = 0; nn < 4; ++nn)
          acc[m][nn] = __builtin_fmaf(a[m], bv[nn], acc[m][nn]);
    }

    __builtin_amdgcn_s_barrier();
#pragma unroll
    for (int i = 0; i < 4; ++i) {
      int e = i * 1024 + tid * 4;
      const float* ga = gb + (size_t)(e >> 6) * NPTS + jnext + (e & 63);
      __builtin_amdgcn_global_load_lds((gptr_t)ga, (lptr_t)(colA + e), 16, 0, 0);
    }
    asm volatile("s_waitcnt vmcnt(4)" ::: "memory");
    __builtin_amdgcn_s_barrier();

#pragma unroll 8
    for (int k2 = 0; k2 < 64; ++k2) {
      float a[4], bv[4];
      *(float4*)a  = *(const float4*)&rowT[64 + k2][ty * 4];
      *(float4*)bv = *(const float4*)(colB + k2 * 64 + tx * 4);
#pragma unroll
      for (int m = 0; m < 4; ++m)
#pragma unroll
        for (int nn = 0; nn < 4; ++nn)
          acc[m][nn] = __builtin_fmaf(a[m], bv[nn], acc[m][nn]);
    }

#pragma unroll
    for (int nn = 0; nn < 4; ++nn) {
      int j = jt + tx * 4 + nn;
      float xc = xx[(size_t)b * NPTS + j];
#pragma unroll
      for (int m = 0; m < 4; ++m) {
        float val = __fsub_rn(__fsub_rn(__fmul_rn(2.0f, acc[m][nn]), xr[m]), xc);
        if (val > tv[m][8]) {
          float cv = val; int ci = j;
#pragma unroll
          for (int s = 0; s < 9; ++s) {
            bool sw = cv > tv[m][s];
            float t1 = tv[m][s]; int t2 = ti[m][s];
            tv[m][s] = sw ? cv : t1;  ti[m][s] = sw ? ci : t2;
            cv = sw ? t1 : cv;        ci = sw ? t2 : ci;
          }
        }
      }
    }
  }

  __syncthreads();
#pragma unroll
  for (int m = 0; m < 4; ++m) {
    int row = ty * 4 + m;
#pragma unroll
    for (int s = 0; s < 9; ++s) {
      mv[row][tx * 9 + s] = tv[m][s];
      mi[row][tx * 9 + s] = (unsigned short)ti[m][s];
    }
  }
  __syncthreads();
  if (tid < 64) {
    int row = tid;
    size_t base = ((size_t)b * NPTS + n0 + row) * KNN;
    for (int s = 0; s < KNN; ++s) {
      float best = -3.4e38f; int bj = 0x7fffffff; int bq = 0;
      for (int q = 0; q < 144; ++q) {
        float v = mv[row][q]; int jj = (int)mi[row][q];
        if (v > best || (v == best && jj < bj)) { best = v; bj = jj; bq = q; }
      }
      mv[row][bq] = -3.4e38f;
      idxout[base + s] = bj;
    }
  }
}

// ---------- K2a: weight prep ----------
__global__ void k_prep(const float* __restrict__ W1, const float* __restrict__ W2,
                       float* __restrict__ At, float* __restrict__ W2t) {
  int g = blockIdx.x * 256 + threadIdx.x;
  if (g < 512 * 128) {
    int k = g / 128, o = g % 128;
    float v;
    if (k < 384) v = W1[(size_t)o * 768 + 384 + k];
    else {
      int c = k - 384;
      v = W1[(size_t)o * 768 + c * 3] + W1[(size_t)o * 768 + c * 3 + 1] +
          W1[(size_t)o * 768 + c * 3 + 2];
    }
    At[(size_t)k * 128 + o] = v;
  }
  if (g < 384 * 128) {
    int k = g / 128, o = g % 128;
    W2t[(size_t)k * 128 + o] = W2[(size_t)o * 384 + k];
  }
}

// ---------- K2: conv1 as K=512 GEMM, B-quad registers + double-buffered AL ----------
// Neighbor phase: 16 chunks x 24 k-rows; chunk kc+1 staged into the alternate
// buffer while computing chunk kc (counted vmcnt(3), raw barriers — no drain).
// k order and FMA order identical to r17 -> h1 bit-identical.
#define NN1 8
__global__ __launch_bounds__(256) void k_conv1(const float* __restrict__ xT,
                                               const int* __restrict__ knn_idx,
                                               const float* __restrict__ At,
                                               const float* __restrict__ bias1,
                                               float* __restrict__ h1) {
  extern __shared__ __align__(16) char sm1[];
  float (*dminL)[KNN][132] = (float (*)[KNN][132])sm1;            // 38016 B
  float (*xnL)[132] = (float (*)[132])(sm1 + 38016);              //  4224 B
  int   (*idxL)[KNN] = (int (*)[KNN])(sm1 + 42240);               //   288 B
  float* ALb = (float*)(sm1 + 42528);                             // 2*3072*4 = 24576 B
  int b = blockIdx.y;
  int n0 = blockIdx.x * NN1;
  int tid = threadIdx.x;

  if (tid < NN1 * KNN) {
    int n = tid / KNN, k = tid % KNN;
    idxL[n][k] = knn_idx[((size_t)b * NPTS + n0 + n) * KNN + k];
  }
  {
    int n = tid >> 5, q = tid & 31;
    float4 v = *(const float4*)&xT[((size_t)b * NPTS + n0 + n) * CH + q * 4];
    *(float4*)&xnL[n][q * 4] = v;
  }
  // prologue: stage chunk 0 -> buf0 (retires during dminL build's own waits)
#pragma unroll
  for (int i = 0; i < 3; ++i) {
    int e = i * 1024 + tid * 4;
    __builtin_amdgcn_global_load_lds((gptr_t)(At + e), (lptr_t)(ALb + e), 16, 0, 0);
  }
  __syncthreads();
#pragma unroll
  for (int i = 0; i < 9; ++i) {
    int e = tid + i * 256;
    int rrow = e >> 5, q = e & 31;
    int n = rrow / KNN, k = rrow % KNN;
    int j = idxL[n][k];
    float4 xj = *(const float4*)&xT[((size_t)b * NPTS + j) * CH + q * 4];
    float4 xn = *(const float4*)&xnL[n][q * 4];
    float4 d;
    d.x = 2.0f * fminf(xn.x - xj.x, 0.0f);
    d.y = 2.0f * fminf(xn.y - xj.y, 0.0f);
    d.z = 2.0f * fminf(xn.z - xj.z, 0.0f);
    d.w = 2.0f * fminf(xn.w - xj.w, 0.0f);
    *(float4*)&dminL[n][k][q * 4] = d;
  }
  __syncthreads();   // dminL + chunk0 visible (full drain once)

  int n = tid & (NN1 - 1);
  int og = tid >> 3;
  float acc[4][3];
#pragma unroll
  for (int o = 0; o < 4; ++o)
#pragma unroll
    for (int t = 0; t < 3; ++t) acc[o][t] = 0.f;

  // ---- neighbor phase: k = 0..383, 16 chunks x 24 k-rows, double-buffered ----
  for (int kc = 0; kc < 16; ++kc) {
    __builtin_amdgcn_s_barrier();   // readers of buf[(kc+1)&1] (iter kc-1) done
    {
      int knext = (kc + 1) & 15;    // wrap: harmless reload of chunk 0
      float* dst = ALb + ((kc + 1) & 1) * 3072;
#pragma unroll
      for (int i = 0; i < 3; ++i) {
        int e = i * 1024 + tid * 4;
        __builtin_amdgcn_global_load_lds((gptr_t)(At + (size_t)knext * 3072 + e),
                                         (lptr_t)(dst + e), 16, 0, 0);
      }
    }
    asm volatile("s_waitcnt vmcnt(3)" ::: "memory");   // chunk kc resident
    __builtin_amdgcn_s_barrier();                      // publish buf[kc&1]

    const float* AL = ALb + (kc & 1) * 3072;
#pragma unroll
    for (int half = 0; half < 2; ++half) {
      int cbase = kc * 8 + half * 4;      // columns cbase..cbase+3
      float q9[9][4];
#pragma unroll
      for (int nr = 0; nr < 9; ++nr)
        *(float4*)q9[nr] = *(const float4*)&dminL[n][nr][cbase];

#pragma unroll
      for (int kk = 0; kk < 12; ++kk) {   // k = kc*24 + half*12 + kk, ascending
        int ci = kk / 3, r = kk % 3;      // compile-time after unroll
        float a[4];
        *(float4*)a = *(const float4*)&AL[(half * 12 + kk) * 128 + og * 4];
#pragma unroll
        for (int o = 0; o < 4; ++o) {
          acc[o][0] = fmaf(a[o], q9[r][ci],     acc[o][0]);
          acc[o][1] = fmaf(a[o], q9[3 + r][ci], acc[o][1]);
          acc[o][2] = fmaf(a[o], q9[6 + r][ci], acc[o][2]);
        }
      }
    }
  }

  // ---- center phase: k = 384..511, 4 chunks x 32 rows (single buffer) ----
  for (int kc2 = 0; kc2 < 4; ++kc2) {
    __syncthreads();   // full drain (also clears wrapped prefetch on first iter)
#pragma unroll
    for (int i = 0; i < 4; ++i) {
      int e = i * 1024 + tid * 4;
      const float* ga = At + (size_t)(384 + kc2 * 32) * 128 + e;
      __builtin_amdgcn_global_load_lds((gptr_t)ga, (lptr_t)(ALb + e), 16, 0, 0);
    }
    asm volatile("s_waitcnt vmcnt(0)" ::: "memory");
    __syncthreads();
#pragma unroll 4
    for (int kk = 0; kk < 32; ++kk) {
      int c = kc2 * 32 + kk;
      float a[4];
      *(float4*)a = *(const float4*)&ALb[kk * 128 + og * 4];
      float b0 = xnL[n][c];
#pragma unroll
      for (int o = 0; o < 4; ++o) {
        acc[o][0] = fmaf(a[o], b0, acc[o][0]);
        acc[o][1] = fmaf(a[o], b0, acc[o][1]);
        acc[o][2] = fmaf(a[o], b0, acc[o][2]);
      }
    }
  }

#pragma unroll
  for (int o = 0; o < 4; ++o) {
    int oo = og * 4 + o;
    float bs = bias1[oo];
    size_t base = ((size_t)(b * CH + oo) * NPTS + n0 + n) * 3;
#pragma unroll
    for (int t = 0; t < 3; ++t) h1[base + t] = acc[o][t] + bs;
  }
}

// ---------- stats: deterministic two-level reduction (f64 accumulation) ----------
__global__ void k_stats_partial(const float* __restrict__ src, double* __restrict__ psum,
                                double* __restrict__ psq, int slablen) {
  __shared__ double ls[256], lq[256];
  int blk = blockIdx.x;
  const float* p = src + (size_t)blk * slablen;
  double s = 0.0, q = 0.0;
  for (int i = threadIdx.x; i < slablen; i += 256) {
    double v = (double)p[i];
    s += v; q = fma(v, v, q);
  }
  ls[threadIdx.x] = s; lq[threadIdx.x] = q;
  __syncthreads();
  for (int off = 128; off > 0; off >>= 1) {
    if (threadIdx.x < off) {
      ls[threadIdx.x] += ls[threadIdx.x + off];
      lq[threadIdx.x] += lq[threadIdx.x + off];
    }
    __syncthreads();
  }
  if (threadIdx.x == 0) { psum[blk] = ls[0]; psq[blk] = lq[0]; }
}

__global__ void k_stats_final(const double* __restrict__ psum, const double* __restrict__ psq,
                              const float* __restrict__ gamma, const float* __restrict__ beta,
                              float* __restrict__ aout, float* __restrict__ cout_,
                              double inv_n) {
  int c = threadIdx.x;
  if (c < CH) {
    double s = 0.0, q = 0.0;
    for (int b = 0; b < BATCH; ++b) { s += psum[b * CH + c]; q += psq[b * CH + c]; }
    double mean = s * inv_n;
    double var = q * inv_n - mean * mean;
    double a = (double)gamma[c] / sqrt(var + 1e-5);
    aout[c] = (float)a;
    cout_[c] = (float)((double)beta[c] - mean * a);
  }
}

// ---------- K4: conv2 (K=384), BN1+ReLU on the fly, double-buffered WL ----------
__global__ __launch_bounds__(256) void k_conv2(const float* __restrict__ h1,
                                               const float* __restrict__ W2t,
                                               const float* __restrict__ bias2,
                                               const float* __restrict__ a1,
                                               const float* __restrict__ c1,
                                               float* __restrict__ out) {
  extern __shared__ __align__(16) char sm2[];
  float (*actL)[36] = (float (*)[36])sm2;        // 384*36*4 = 55296 B
  float* WLb = (float*)(sm2 + 55296);            // 2*2048*4 = 16384 B
  int b = blockIdx.y, n0 = blockIdx.x * 32, tid = threadIdx.x;

  // prologue: stage WL chunk 0 -> buf0
  {
    int e = tid * 4;
    __builtin_amdgcn_global_load_lds((gptr_t)(W2t + e), (lptr_t)(WLb + e), 16, 0, 0);
    __builtin_amdgcn_global_load_lds((gptr_t)(W2t + 1024 + e), (lptr_t)(WLb + 1024 + e), 16, 0, 0);
  }
#pragma unroll
  for (int i = 0; i < 12; ++i) {
    int e = tid + i * 256;
    int c = e / 24, q = e % 24;
    float4 v = *(const float4*)&h1[((size_t)(b * CH + c) * NPTS + n0) * 3 + q * 4];
    float aa = a1[c], cc = c1[c];
    float vv[4] = {v.x, v.y, v.z, v.w};
#pragma unroll
    for (int s = 0; s < 4; ++s) {
      int f = q * 4 + s;
      int nn = f / 3, t = f - nn * 3;
      actL[c * 3 + t][nn] = fmaxf(0.0f, fmaf(vv[s], aa, cc));
    }
  }
  __syncthreads();   // actL + chunk0 visible (full drain once)

  int ng = tid & 7, og = tid >> 3;
  float acc[4][4];
#pragma unroll
  for (int o = 0; o < 4; ++o)
#pragma unroll
    for (int nn = 0; nn < 4; ++nn) acc[o][nn] = 0.f;

  for (int kc = 0; kc < 24; ++kc) {
    __builtin_amdgcn_s_barrier();   // readers of buf[(kc+1)&1] done
    {
      int knext = kc + 1 == 24 ? 23 : kc + 1;   // wrap: harmless reload
      float* dst = WLb + ((kc + 1) & 1) * 2048;
      int e = tid * 4;
      __builtin_amdgcn_global_load_lds((gptr_t)(W2t + (size_t)knext * 2048 + e),
                                       (lptr_t)(dst + e), 16, 0, 0);
      __builtin_amdgcn_global_load_lds((gptr_t)(W2t + (size_t)knext * 2048 + 1024 + e),
                                       (lptr_t)(dst + 1024 + e), 16, 0, 0);
    }
    asm volatile("s_waitcnt vmcnt(2)" ::: "memory");   // chunk kc resident
    __builtin_amdgcn_s_barrier();                      // publish buf[kc&1]

    const float* WL = WLb + (kc & 1) * 2048;
#pragma unroll 4
    for (int kk = 0; kk < 16; ++kk) {
      float a[4], bv[4];
      *(float4*)a  = *(const float4*)&WL[kk * 128 + og * 4];
      *(float4*)bv = *(const float4*)&actL[kc * 16 + kk][ng * 4];
#pragma unroll
      for (int o = 0; o < 4; ++o)
#pragma unroll
        for (int nn = 0; nn < 4; ++nn) acc[o][nn] = fmaf(a[o], bv[nn], acc[o][nn]);
    }
  }
  __syncthreads();   // drain wrapped prefetch before block exit

#pragma unroll
  for (int o = 0; o < 4; ++o) {
    int oo = og * 4 + o;
    float bs = bias2[oo];
    size_t base = (size_t)(b * CH + oo) * NPTS + n0 + ng * 4;
#pragma unroll
    for (int nn = 0; nn < 4; ++nn) out[base + nn] = acc[o][nn] + bs;
  }
}

// ---------- K6: final BN2+ReLU in place on d_out ----------
__global__ void k_bnrelu(float* __restrict__ out, const float* __restrict__ a2,
                         const float* __restrict__ c2) {
  int g = blockIdx.x * 256 + threadIdx.x;
  int c = (g >> 11) & 127;
  float v = out[g];
  out[g] = fmaxf(0.0f, fmaf(v, a2[c], c2[c]));
}

extern "C" void kernel_launch(void* const* d_in, const int* in_sizes, int n_in,
                              void* d_out, int out_size, void* d_ws, size_t ws_size,
                              hipStream_t stream) {
  const float* x   = (const float*)d_in[0];
  const float* W1  = (const float*)d_in[1];
  const float* b1  = (const float*)d_in[2];
  const float* g1  = (const float*)d_in[3];
  const float* be1 = (const float*)d_in[4];
  const float* W2  = (const float*)d_in[5];
  const float* b2  = (const float*)d_in[6];
  const float* g2  = (const float*)d_in[7];
  const float* be2 = (const float*)d_in[8];
  float* out = (float*)d_out;

  char* ws = (char*)d_ws;
  float*  xT      = (float*) (ws);                 // 16,777,216 B
  float*  xx      = (float*) (ws + 16777216);      //    131,072 B
  int*    knn_idx = (int*)   (ws + 16908288);      //  1,179,648 B
  float*  At      = (float*) (ws + 18087936);      //    262,144 B
  float*  W2t     = (float*) (ws + 18350080);      //    196,608 B
  float*  h1      = (float*) (ws + 18546688);      // 50,331,648 B
  double* psum    = (double*)(ws + 68878336);      //     16,384 B
  double* psq     = (double*)(ws + 68894720);      //     16,384 B
  float*  a1      = (float*) (ws + 68911104);
  float*  c1      = (float*) (ws + 68911616);
  float*  a2      = (float*) (ws + 68912128);
  float*  c2      = (float*) (ws + 68912640);

  (void)hipFuncSetAttribute((const void*)k_conv1,
                            hipFuncAttributeMaxDynamicSharedMemorySize, 67104);
  (void)hipFuncSetAttribute((const void*)k_conv2,
                            hipFuncAttributeMaxDynamicSharedMemorySize, 71680);

  k_transpose<<<dim3(NPTS / 32, CH / 32, BATCH), dim3(32, 8), 0, stream>>>(x, xT);
  k_xx_pw<<<(BATCH * NPTS) / 256, 256, 0, stream>>>(x, xx);
  k_knn_np<<<dim3(NPTS / 64, BATCH), 256, 0, stream>>>(x, xx, knn_idx);
  k_prep<<<256, 256, 0, stream>>>(W1, W2, At, W2t);
  k_conv1<<<dim3(NPTS / NN1, BATCH), 256, 67104, stream>>>(xT, knn_idx, At, b1, h1);
  k_stats_partial<<<BATCH * CH, 256, 0, stream>>>(h1, psum, psq, NPTS * 3);
  k_stats_final<<<1, 128, 0, stream>>>(psum, psq, g1, be1, a1, c1,
                                       1.0 / (double)(BATCH * NPTS * 3));
  k_conv2<<<dim3(NPTS / 32, BATCH), 256, 71680, stream>>>(h1, W2t, b2, a1, c1, out);
  k_stats_partial<<<BATCH * CH, 256, 0, stream>>>(out, psum, psq, NPTS);
  k_stats_final<<<1, 128, 0, stream>>>(psum, psq, g2, be2, a2, c2,
                                       1.0 / (double)(BATCH * NPTS));
  k_bnrelu<<<(BATCH * CH * NPTS) / 256, 256, 0, stream>>>(out, a2, c2);
}

// Round 19
// 788.916 us; speedup vs baseline: 1.0291x; 1.0291x over previous
//
#include <hip/hip_runtime.h>
#include <cstddef>

#define BATCH 16
#define CH    128
#define NPTS  2048
#define KNN   9

typedef const __attribute__((address_space(1))) void* gptr_t;
typedef __attribute__((address_space(3))) void* lptr_t;

// ---------- K0: transpose x (B,C,N) -> xT (B,N,C) ----------
__global__ void k_transpose(const float* __restrict__ x, float* __restrict__ xT) {
  __shared__ float tile[32][33];
  int b = blockIdx.z;
  int n0 = blockIdx.x * 32, c0 = blockIdx.y * 32;
  int tx = threadIdx.x, ty = threadIdx.y;
#pragma unroll
  for (int i = 0; i < 4; ++i) {
    int cc = c0 + ty + i * 8;
    tile[ty + i * 8][tx] = x[((size_t)b * CH + cc) * NPTS + n0 + tx];
  }
  __syncthreads();
#pragma unroll
  for (int i = 0; i < 4; ++i) {
    int nn = n0 + ty + i * 8;
    xT[((size_t)b * NPTS + nn) * CH + c0 + tx] = tile[tx][ty + i * 8];
  }
}

// ---------- K0b: xx via numpy AVX512 pairwise-sum model (bit-exact, verified) ----------
__global__ void k_xx_pw(const float* __restrict__ x, float* __restrict__ xx) {
  int g = blockIdx.x * 256 + threadIdx.x;   // b*NPTS + n
  int b = g >> 11, n = g & (NPTS - 1);
  const float* p = x + (size_t)b * CH * NPTS + n;
  float s[128];
#pragma unroll
  for (int c = 0; c < 128; ++c) {
    float v = p[(size_t)c * NPTS];
    s[c] = __fmul_rn(v, v);
  }
  float lane[16];
#pragma unroll
  for (int l = 0; l < 16; ++l) {
    lane[l] = __fadd_rn(
        __fadd_rn(__fadd_rn(s[l], s[16 + l]), __fadd_rn(s[32 + l], s[48 + l])),
        __fadd_rn(__fadd_rn(s[64 + l], s[80 + l]), __fadd_rn(s[96 + l], s[112 + l])));
  }
  float m8[8];
#pragma unroll
  for (int i = 0; i < 8; ++i) m8[i] = __fadd_rn(lane[i], lane[i + 8]);
  float n4[4];
#pragma unroll
  for (int i = 0; i < 4; ++i) n4[i] = __fadd_rn(m8[i], m8[i + 4]);
  float p2[2];
#pragma unroll
  for (int i = 0; i < 2; ++i) p2[i] = __fadd_rn(n4[i], n4[i + 2]);
  xx[g] = __fadd_rn(p2[0], p2[1]);
}

// ---------- K1: 64x64 tile + K-split double-buffered colT (r15 structure, ~521us) ----------
__global__ __launch_bounds__(256) void k_knn_np(const float* __restrict__ x,
                                                const float* __restrict__ xx,
                                                int* __restrict__ idxout) {
  __shared__ __align__(16) char smraw[65536];
  float (*rowT)[64] = (float (*)[64])smraw;                       // [128][64] 32KB
  float* colA = (float*)(smraw + 32768);                          // [64][64] 16KB
  float* colB = (float*)(smraw + 49152);                          // [64][64] 16KB
  float (*mv)[145] = (float (*)[145])smraw;                       // merge overlay
  unsigned short (*mi)[145] = (unsigned short (*)[145])(smraw + 37120);

  int b = blockIdx.y;
  int n0 = blockIdx.x * 64;
  int tid = threadIdx.x;
  int tx = tid & 15, ty = tid >> 4;

  const float* gb = x + (size_t)b * CH * NPTS;

#pragma unroll
  for (int i = 0; i < 8; ++i) {
    int e = i * 1024 + tid * 4;
    const float* ga = gb + (size_t)(e >> 6) * NPTS + n0 + (e & 63);
    __builtin_amdgcn_global_load_lds((gptr_t)ga, (lptr_t)(&rowT[0][0] + e), 16, 0, 0);
  }

  float tv[4][9];
  int   ti[4][9];
#pragma unroll
  for (int m = 0; m < 4; ++m)
#pragma unroll
    for (int s = 0; s < 9; ++s) { tv[m][s] = -3.4e38f; ti[m][s] = 0x7fffffff; }

  float xr[4];
#pragma unroll
  for (int m = 0; m < 4; ++m) xr[m] = xx[(size_t)b * NPTS + n0 + ty * 4 + m];

#pragma unroll
  for (int i = 0; i < 4; ++i) {
    int e = i * 1024 + tid * 4;
    const float* ga = gb + (size_t)(e >> 6) * NPTS + 0 + (e & 63);
    __builtin_amdgcn_global_load_lds((gptr_t)ga, (lptr_t)(colA + e), 16, 0, 0);
  }

  for (int jt = 0; jt < NPTS; jt += 64) {
    int jnext = (jt + 64) & (NPTS - 1);

    __builtin_amdgcn_s_barrier();
#pragma unroll
    for (int i = 0; i < 4; ++i) {
      int e = i * 1024 + tid * 4;
      const float* ga = gb + (size_t)(64 + (e >> 6)) * NPTS + jt + (e & 63);
      __builtin_amdgcn_global_load_lds((gptr_t)ga, (lptr_t)(colB + e), 16, 0, 0);
    }
    asm volatile("s_waitcnt vmcnt(4)" ::: "memory");
    __builtin_amdgcn_s_barrier();

    float acc[4][4];
#pragma unroll
    for (int m = 0; m < 4; ++m)
#pragma unroll
      for (int nn = 0; nn < 4; ++nn) acc[m][nn] = 0.f;

#pragma unroll 8
    for (int k2 = 0; k2 < 64; ++k2) {
      float a[4], bv[4];
      *(float4*)a  = *(const float4*)&rowT[k2][ty * 4];
      *(float4*)bv = *(const float4*)(colA + k2 * 64 + tx * 4);
#pragma unroll
      for (int m = 0; m < 4; ++m)
#pragma unroll
        for (int nn = 0; nn < 4; ++nn)
          acc[m][nn] = __builtin_fmaf(a[m], bv[nn], acc[m][nn]);
    }

    __builtin_amdgcn_s_barrier();
#pragma unroll
    for (int i = 0; i < 4; ++i) {
      int e = i * 1024 + tid * 4;
      const float* ga = gb + (size_t)(e >> 6) * NPTS + jnext + (e & 63);
      __builtin_amdgcn_global_load_lds((gptr_t)ga, (lptr_t)(colA + e), 16, 0, 0);
    }
    asm volatile("s_waitcnt vmcnt(4)" ::: "memory");
    __builtin_amdgcn_s_barrier();

#pragma unroll 8
    for (int k2 = 0; k2 < 64; ++k2) {
      float a[4], bv[4];
      *(float4*)a  = *(const float4*)&rowT[64 + k2][ty * 4];
      *(float4*)bv = *(const float4*)(colB + k2 * 64 + tx * 4);
#pragma unroll
      for (int m = 0; m < 4; ++m)
#pragma unroll
        for (int nn = 0; nn < 4; ++nn)
          acc[m][nn] = __builtin_fmaf(a[m], bv[nn], acc[m][nn]);
    }

#pragma unroll
    for (int nn = 0; nn < 4; ++nn) {
      int j = jt + tx * 4 + nn;
      float xc = xx[(size_t)b * NPTS + j];
#pragma unroll
      for (int m = 0; m < 4; ++m) {
        float val = __fsub_rn(__fsub_rn(__fmul_rn(2.0f, acc[m][nn]), xr[m]), xc);
        if (val > tv[m][8]) {
          float cv = val; int ci = j;
#pragma unroll
          for (int s = 0; s < 9; ++s) {
            bool sw = cv > tv[m][s];
            float t1 = tv[m][s]; int t2 = ti[m][s];
            tv[m][s] = sw ? cv : t1;  ti[m][s] = sw ? ci : t2;
            cv = sw ? t1 : cv;        ci = sw ? t2 : ci;
          }
        }
      }
    }
  }

  __syncthreads();
#pragma unroll
  for (int m = 0; m < 4; ++m) {
    int row = ty * 4 + m;
#pragma unroll
    for (int s = 0; s < 9; ++s) {
      mv[row][tx * 9 + s] = tv[m][s];
      mi[row][tx * 9 + s] = (unsigned short)ti[m][s];
    }
  }
  __syncthreads();
  if (tid < 64) {
    int row = tid;
    size_t base = ((size_t)b * NPTS + n0 + row) * KNN;
    for (int s = 0; s < KNN; ++s) {
      float best = -3.4e38f; int bj = 0x7fffffff; int bq = 0;
      for (int q = 0; q < 144; ++q) {
        float v = mv[row][q]; int jj = (int)mi[row][q];
        if (v > best || (v == best && jj < bj)) { best = v; bj = jj; bq = q; }
      }
      mv[row][bq] = -3.4e38f;
      idxout[base + s] = bj;
    }
  }
}

// ---------- K2a: weight prep ----------
__global__ void k_prep(const float* __restrict__ W1, const float* __restrict__ W2,
                       float* __restrict__ At, float* __restrict__ W2t) {
  int g = blockIdx.x * 256 + threadIdx.x;
  if (g < 512 * 128) {
    int k = g / 128, o = g % 128;
    float v;
    if (k < 384) v = W1[(size_t)o * 768 + 384 + k];
    else {
      int c = k - 384;
      v = W1[(size_t)o * 768 + c * 3] + W1[(size_t)o * 768 + c * 3 + 1] +
          W1[(size_t)o * 768 + c * 3 + 2];
    }
    At[(size_t)k * 128 + o] = v;
  }
  if (g < 384 * 128) {
    int k = g / 128, o = g % 128;
    W2t[(size_t)k * 128 + o] = W2[(size_t)o * 384 + k];
  }
}

// ---------- K2: conv1 as K=512 GEMM, B-quad register scheme (r17, best) ----------
#define NN1 8
__global__ __launch_bounds__(256) void k_conv1(const float* __restrict__ xT,
                                               const int* __restrict__ knn_idx,
                                               const float* __restrict__ At,
                                               const float* __restrict__ bias1,
                                               float* __restrict__ h1) {
  __shared__ float dminL[NN1][KNN][132];
  __shared__ float xnL[NN1][132];
  __shared__ __align__(16) float AL[32][128];
  __shared__ int   idxL[NN1][KNN];
  int b = blockIdx.y;
  int n0 = blockIdx.x * NN1;
  int tid = threadIdx.x;

  if (tid < NN1 * KNN) {
    int n = tid / KNN, k = tid % KNN;
    idxL[n][k] = knn_idx[((size_t)b * NPTS + n0 + n) * KNN + k];
  }
  {
    int n = tid >> 5, q = tid & 31;
    float4 v = *(const float4*)&xT[((size_t)b * NPTS + n0 + n) * CH + q * 4];
    *(float4*)&xnL[n][q * 4] = v;
  }
  __syncthreads();
#pragma unroll
  for (int i = 0; i < 9; ++i) {
    int e = tid + i * 256;
    int rrow = e >> 5, q = e & 31;
    int n = rrow / KNN, k = rrow % KNN;
    int j = idxL[n][k];
    float4 xj = *(const float4*)&xT[((size_t)b * NPTS + j) * CH + q * 4];
    float4 xn = *(const float4*)&xnL[n][q * 4];
    float4 d;
    d.x = 2.0f * fminf(xn.x - xj.x, 0.0f);
    d.y = 2.0f * fminf(xn.y - xj.y, 0.0f);
    d.z = 2.0f * fminf(xn.z - xj.z, 0.0f);
    d.w = 2.0f * fminf(xn.w - xj.w, 0.0f);
    *(float4*)&dminL[n][k][q * 4] = d;
  }

  int n = tid & (NN1 - 1);
  int og = tid >> 3;
  float acc[4][3];
#pragma unroll
  for (int o = 0; o < 4; ++o)
#pragma unroll
    for (int t = 0; t < 3; ++t) acc[o][t] = 0.f;

  // ---- neighbor phase: k = 0..383, 16 chunks x 24 k-rows (2 column-quads) ----
  for (int kc = 0; kc < 16; ++kc) {
    __syncthreads();
#pragma unroll
    for (int i = 0; i < 3; ++i) {
      int e = i * 1024 + tid * 4;
      const float* ga = At + (size_t)kc * 3072 + e;
      __builtin_amdgcn_global_load_lds((gptr_t)ga, (lptr_t)(&AL[0][0] + e), 16, 0, 0);
    }
    asm volatile("s_waitcnt vmcnt(0)" ::: "memory");
    __syncthreads();

#pragma unroll
    for (int half = 0; half < 2; ++half) {
      int cbase = kc * 8 + half * 4;      // columns cbase..cbase+3
      float q9[9][4];
#pragma unroll
      for (int nr = 0; nr < 9; ++nr)
        *(float4*)q9[nr] = *(const float4*)&dminL[n][nr][cbase];

#pragma unroll
      for (int kk = 0; kk < 12; ++kk) {   // k = kc*24 + half*12 + kk, ascending
        int ci = kk / 3, r = kk % 3;      // compile-time after unroll
        float a[4];
        *(float4*)a = *(const float4*)&AL[half * 12 + kk][og * 4];
#pragma unroll
        for (int o = 0; o < 4; ++o) {
          acc[o][0] = fmaf(a[o], q9[r][ci],     acc[o][0]);
          acc[o][1] = fmaf(a[o], q9[3 + r][ci], acc[o][1]);
          acc[o][2] = fmaf(a[o], q9[6 + r][ci], acc[o][2]);
        }
      }
    }
  }

  // ---- center phase: k = 384..511, 4 chunks x 32 rows ----
  for (int kc2 = 0; kc2 < 4; ++kc2) {
    __syncthreads();
#pragma unroll
    for (int i = 0; i < 4; ++i) {
      int e = i * 1024 + tid * 4;
      const float* ga = At + (size_t)(384 + kc2 * 32) * 128 + e;
      __builtin_amdgcn_global_load_lds((gptr_t)ga, (lptr_t)(&AL[0][0] + e), 16, 0, 0);
    }
    asm volatile("s_waitcnt vmcnt(0)" ::: "memory");
    __syncthreads();
#pragma unroll 4
    for (int kk = 0; kk < 32; ++kk) {
      int c = kc2 * 32 + kk;
      float a[4];
      *(float4*)a = *(const float4*)&AL[kk][og * 4];
      float b0 = xnL[n][c];
#pragma unroll
      for (int o = 0; o < 4; ++o) {
        acc[o][0] = fmaf(a[o], b0, acc[o][0]);
        acc[o][1] = fmaf(a[o], b0, acc[o][1]);
        acc[o][2] = fmaf(a[o], b0, acc[o][2]);
      }
    }
  }

#pragma unroll
  for (int o = 0; o < 4; ++o) {
    int oo = og * 4 + o;
    float bs = bias1[oo];
    size_t base = ((size_t)(b * CH + oo) * NPTS + n0 + n) * 3;
#pragma unroll
    for (int t = 0; t < 3; ++t) h1[base + t] = acc[o][t] + bs;
  }
}

// ---------- stats: deterministic two-level reduction (f64 accumulation) ----------
__global__ void k_stats_partial(const float* __restrict__ src, double* __restrict__ psum,
                                double* __restrict__ psq, int slablen) {
  __shared__ double ls[256], lq[256];
  int blk = blockIdx.x;
  const float* p = src + (size_t)blk * slablen;
  double s = 0.0, q = 0.0;
  for (int i = threadIdx.x; i < slablen; i += 256) {
    double v = (double)p[i];
    s += v; q = fma(v, v, q);
  }
  ls[threadIdx.x] = s; lq[threadIdx.x] = q;
  __syncthreads();
  for (int off = 128; off > 0; off >>= 1) {
    if (threadIdx.x < off) {
      ls[threadIdx.x] += ls[threadIdx.x + off];
      lq[threadIdx.x] += lq[threadIdx.x + off];
    }
    __syncthreads();
  }
  if (threadIdx.x == 0) { psum[blk] = ls[0]; psq[blk] = lq[0]; }
}

__global__ void k_stats_final(const double* __restrict__ psum, const double* __restrict__ psq,
                              const float* __restrict__ gamma, const float* __restrict__ beta,
                              float* __restrict__ aout, float* __restrict__ cout_,
                              double inv_n) {
  int c = threadIdx.x;
  if (c < CH) {
    double s = 0.0, q = 0.0;
    for (int b = 0; b < BATCH; ++b) { s += psum[b * CH + c]; q += psq[b * CH + c]; }
    double mean = s * inv_n;
    double var = q * inv_n - mean * mean;
    double a = (double)gamma[c] / sqrt(var + 1e-5);
    aout[c] = (float)a;
    cout_[c] = (float)((double)beta[c] - mean * a);
  }
}

// ---------- K4: conv2 (K=384), BN1+ReLU on the fly; writes raw h2 -> d_out ----------
__global__ __launch_bounds__(256) void k_conv2(const float* __restrict__ h1,
                                               const float* __restrict__ W2t,
                                               const float* __restrict__ bias2,
                                               const float* __restrict__ a1,
                                               const float* __restrict__ c1,
                                               float* __restrict__ out) {
  __shared__ float actL[384][36];
  __shared__ __align__(16) float WL[16][128];
  int b = blockIdx.y, n0 = blockIdx.x * 32, tid = threadIdx.x;
#pragma unroll
  for (int i = 0; i < 12; ++i) {
    int e = tid + i * 256;
    int c = e / 24, q = e % 24;
    float4 v = *(const float4*)&h1[((size_t)(b * CH + c) * NPTS + n0) * 3 + q * 4];
    float aa = a1[c], cc = c1[c];
    float vv[4] = {v.x, v.y, v.z, v.w};
#pragma unroll
    for (int s = 0; s < 4; ++s) {
      int f = q * 4 + s;
      int nn = f / 3, t = f - nn * 3;
      actL[c * 3 + t][nn] = fmaxf(0.0f, fmaf(vv[s], aa, cc));
    }
  }
  int ng = tid & 7, og = tid >> 3;
  float acc[4][4];
#pragma unroll
  for (int o = 0; o < 4; ++o)
#pragma unroll
    for (int nn = 0; nn < 4; ++nn) acc[o][nn] = 0.f;

  for (int kc = 0; kc < 24; ++kc) {
    __syncthreads();
    {
      int e = tid * 4;
      const float* ga = W2t + (size_t)kc * 2048 + e;
      __builtin_amdgcn_global_load_lds((gptr_t)ga, (lptr_t)(&WL[0][0] + e), 16, 0, 0);
      ga += 1024;
      __builtin_amdgcn_global_load_lds((gptr_t)ga, (lptr_t)(&WL[0][0] + 1024 + e), 16, 0, 0);
    }
    asm volatile("s_waitcnt vmcnt(0)" ::: "memory");
    __syncthreads();
#pragma unroll 4
    for (int kk = 0; kk < 16; ++kk) {
      float a[4], bv[4];
      *(float4*)a  = *(const float4*)&WL[kk][og * 4];
      *(float4*)bv = *(const float4*)&actL[kc * 16 + kk][ng * 4];
#pragma unroll
      for (int o = 0; o < 4; ++o)
#pragma unroll
        for (int nn = 0; nn < 4; ++nn) acc[o][nn] = fmaf(a[o], bv[nn], acc[o][nn]);
    }
  }
#pragma unroll
  for (int o = 0; o < 4; ++o) {
    int oo = og * 4 + o;
    float bs = bias2[oo];
    size_t base = (size_t)(b * CH + oo) * NPTS + n0 + ng * 4;
#pragma unroll
    for (int nn = 0; nn < 4; ++nn) out[base + nn] = acc[o][nn] + bs;
  }
}

// ---------- K6: final BN2+ReLU in place on d_out ----------
__global__ void k_bnrelu(float* __restrict__ out, const float* __restrict__ a2,
                         const float* __restrict__ c2) {
  int g = blockIdx.x * 256 + threadIdx.x;
  int c = (g >> 11) & 127;
  float v = out[g];
  out[g] = fmaxf(0.0f, fmaf(v, a2[c], c2[c]));
}

extern "C" void kernel_launch(void* const* d_in, const int* in_sizes, int n_in,
                              void* d_out, int out_size, void* d_ws, size_t ws_size,
                              hipStream_t stream) {
  const float* x   = (const float*)d_in[0];
  const float* W1  = (const float*)d_in[1];
  const float* b1  = (const float*)d_in[2];
  const float* g1  = (const float*)d_in[3];
  const float* be1 = (const float*)d_in[4];
  const float* W2  = (const float*)d_in[5];
  const float* b2  = (const float*)d_in[6];
  const float* g2  = (const float*)d_in[7];
  const float* be2 = (const float*)d_in[8];
  float* out = (float*)d_out;

  char* ws = (char*)d_ws;
  float*  xT      = (float*) (ws);                 // 16,777,216 B
  float*  xx      = (float*) (ws + 16777216);      //    131,072 B
  int*    knn_idx = (int*)   (ws + 16908288);      //  1,179,648 B
  float*  At      = (float*) (ws + 18087936);      //    262,144 B
  float*  W2t     = (float*) (ws + 18350080);      //    196,608 B
  float*  h1      = (float*) (ws + 18546688);      // 50,331,648 B
  double* psum    = (double*)(ws + 68878336);      //     16,384 B
  double* psq     = (double*)(ws + 68894720);      //     16,384 B
  float*  a1      = (float*) (ws + 68911104);
  float*  c1      = (float*) (ws + 68911616);
  float*  a2      = (float*) (ws + 68912128);
  float*  c2      = (float*) (ws + 68912640);

  k_transpose<<<dim3(NPTS / 32, CH / 32, BATCH), dim3(32, 8), 0, stream>>>(x, xT);
  k_xx_pw<<<(BATCH * NPTS) / 256, 256, 0, stream>>>(x, xx);
  k_knn_np<<<dim3(NPTS / 64, BATCH), 256, 0, stream>>>(x, xx, knn_idx);
  k_prep<<<256, 256, 0, stream>>>(W1, W2, At, W2t);
  k_conv1<<<dim3(NPTS / NN1, BATCH), 256, 0, stream>>>(xT, knn_idx, At, b1, h1);
  k_stats_partial<<<BATCH * CH, 256, 0, stream>>>(h1, psum, psq, NPTS * 3);
  k_stats_final<<<1, 128, 0, stream>>>(psum, psq, g1, be1, a1, c1,
                                       1.0 / (double)(BATCH * NPTS * 3));
  k_conv2<<<dim3(NPTS / 32, BATCH), 256, 0, stream>>>(h1, W2t, b2, a1, c1, out);
  k_stats_partial<<<BATCH * CH, 256, 0, stream>>>(out, psum, psq, NPTS);
  k_stats_final<<<1, 128, 0, stream>>>(psum, psq, g2, be2, a2, c2,
                                       1.0 / (double)(BATCH * NPTS));
  k_bnrelu<<<(BATCH * CH * NPTS) / 256, 256, 0, stream>>>(out, a2, c2);
}